// Round 6
// baseline (163.344 us; speedup 1.0000x reference)
//
#include <hip/hip_runtime.h>

#define HIDDEN  128
#define N_NODES 100000
#define N_EDGES 2000000
#define NBLK    1024
#define NTHR    256

typedef float f32x4 __attribute__((ext_vector_type(4)));
typedef int   i32x4 __attribute__((ext_vector_type(4)));

// Fused: phase 1 computes per-node dot products into tables in d_ws,
// software grid barrier (1024 blocks = 4/CU at 28 VGPR -> all resident),
// phase 2 gathers the tables per edge. Barrier counter is memset to 0 on
// the stream before each launch (graph-capture-safe, deterministic).
__global__ __launch_bounds__(NTHR) void fused_edge_decoder(
    const float* __restrict__ x_src,
    const float* __restrict__ x_dst,
    const int*   __restrict__ idx,     // [2*N_EDGES]
    const float* __restrict__ w,       // [256]
    const float* __restrict__ bias,    // [1]
    float* __restrict__ out,           // [N_EDGES]
    float* __restrict__ s_tab,         // [N_NODES]   (in d_ws)
    float* __restrict__ d_tab,         // [N_NODES]   (in d_ws)
    int*   __restrict__ barrier_ct)    // [1]         (in d_ws, pre-zeroed)
{
    const int tid      = blockIdx.x * NTHR + threadIdx.x;  // 0 .. 262143
    const int nthreads = NBLK * NTHR;                      // 262144
    const int lane     = tid & 15;

    // ---------------- Phase 1: per-node dots ----------------
    // 16 lanes per node, each lane covers 8 of 128 floats (2x float4).
    // A wave = 4 consecutive nodes -> 2KB contiguous per table (coalesced).
    const f32x4* wv = reinterpret_cast<const f32x4*>(w);
    const f32x4 ws0 = wv[lane];
    const f32x4 ws1 = wv[lane + 16];
    const f32x4 wd0 = wv[lane + 32];
    const f32x4 wd1 = wv[lane + 48];

    const int group   = tid >> 4;        // 0 .. 16383
    const int ngroups = nthreads >> 4;   // 16384

    #pragma unroll 2
    for (int node = group; node < N_NODES; node += ngroups) {
        const f32x4* xs = reinterpret_cast<const f32x4*>(x_src + (size_t)node * HIDDEN);
        const f32x4* xd = reinterpret_cast<const f32x4*>(x_dst + (size_t)node * HIDDEN);
        const f32x4 a0 = xs[lane];
        const f32x4 a1 = xs[lane + 16];
        const f32x4 b0 = xd[lane];
        const f32x4 b1 = xd[lane + 16];

        float ss = a0.x*ws0.x + a0.y*ws0.y + a0.z*ws0.z + a0.w*ws0.w
                 + a1.x*ws1.x + a1.y*ws1.y + a1.z*ws1.z + a1.w*ws1.w;
        float dd = b0.x*wd0.x + b0.y*wd0.y + b0.z*wd0.z + b0.w*wd0.w
                 + b1.x*wd1.x + b1.y*wd1.y + b1.z*wd1.z + b1.w*wd1.w;

        #pragma unroll
        for (int off = 8; off; off >>= 1) {
            ss += __shfl_xor(ss, off);
            dd += __shfl_xor(dd, off);
        }
        if (lane == 0) {
            s_tab[node] = ss;
            d_tab[node] = dd;
        }
    }

    // ---------------- Grid-wide barrier ----------------
    __syncthreads();
    if (threadIdx.x == 0) {
        // Release our table writes at device scope, count in, spin.
        __hip_atomic_fetch_add(barrier_ct, 1, __ATOMIC_RELEASE, __HIP_MEMORY_SCOPE_AGENT);
        while (__hip_atomic_load(barrier_ct, __ATOMIC_ACQUIRE, __HIP_MEMORY_SCOPE_AGENT) < NBLK) {
            __builtin_amdgcn_s_sleep(2);
        }
    }
    __syncthreads();

    // ---------------- Phase 2: per-edge gather ----------------
    // 8 edges per thread, one pass (250000 active threads of 262144).
    const float bv = bias[0];
    const i32x4* ia = reinterpret_cast<const i32x4*>(idx);
    const i32x4* ib = reinterpret_cast<const i32x4*>(idx + N_EDGES);
    f32x4* ov = reinterpret_cast<f32x4*>(out);
    const int nt = N_EDGES / 8;          // 250000

    if (tid < nt) {
        const int t = tid;
        const i32x4 a0 = __builtin_nontemporal_load(ia + 2 * t);
        const i32x4 a1 = __builtin_nontemporal_load(ia + 2 * t + 1);
        const i32x4 b0 = __builtin_nontemporal_load(ib + 2 * t);
        const i32x4 b1 = __builtin_nontemporal_load(ib + 2 * t + 1);

        f32x4 o0, o1;
        o0.x = s_tab[a0.x] + d_tab[b0.x] + bv;
        o0.y = s_tab[a0.y] + d_tab[b0.y] + bv;
        o0.z = s_tab[a0.z] + d_tab[b0.z] + bv;
        o0.w = s_tab[a0.w] + d_tab[b0.w] + bv;
        o1.x = s_tab[a1.x] + d_tab[b1.x] + bv;
        o1.y = s_tab[a1.y] + d_tab[b1.y] + bv;
        o1.z = s_tab[a1.z] + d_tab[b1.z] + bv;
        o1.w = s_tab[a1.w] + d_tab[b1.w] + bv;

        __builtin_nontemporal_store(o0, ov + 2 * t);
        __builtin_nontemporal_store(o1, ov + 2 * t + 1);
    }
}

extern "C" void kernel_launch(void* const* d_in, const int* in_sizes, int n_in,
                              void* d_out, int out_size, void* d_ws, size_t ws_size,
                              hipStream_t stream) {
    const float* x_src = (const float*)d_in[0];
    const float* x_dst = (const float*)d_in[1];
    const int*   idx   = (const int*)d_in[2];
    const float* w     = (const float*)d_in[3];
    const float* bias  = (const float*)d_in[4];
    float* out = (float*)d_out;

    float* s_tab = (float*)d_ws;
    float* d_tab = s_tab + N_NODES;
    int*   barrier_ct = (int*)(d_tab + N_NODES);

    // Reset the barrier counter every call (deterministic across graph replays).
    hipMemsetAsync(barrier_ct, 0, sizeof(int), stream);

    fused_edge_decoder<<<NBLK, NTHR, 0, stream>>>(
        x_src, x_dst, idx, w, bias, out, s_tab, d_tab, barrier_ct);
}

// Round 7
// 144.480 us; speedup vs baseline: 1.1306x; 1.1306x over previous
//
#include <hip/hip_runtime.h>

#define HIDDEN  128
#define N_NODES 100000
#define N_EDGES 2000000
#define NBLK    1024
#define NTHR    256

typedef float f32x4 __attribute__((ext_vector_type(4)));
typedef int   i32x4 __attribute__((ext_vector_type(4)));

// Fused: phase 1 computes per-node dot products into tables in d_ws,
// software grid barrier (1024 blocks = 4/CU at 24 VGPR -> all resident),
// phase 2 gathers the tables per edge.
//
// Barrier discipline (the round-6 lesson): ONE release-add per block to
// publish table writes (L2 writeback), RELAXED polls while spinning (no
// per-poll cache maintenance), ONE agent acquire fence on exit.
__global__ __launch_bounds__(NTHR) void fused_edge_decoder(
    const float* __restrict__ x_src,
    const float* __restrict__ x_dst,
    const int*   __restrict__ idx,     // [2*N_EDGES]
    const float* __restrict__ w,       // [256]
    const float* __restrict__ bias,    // [1]
    float* __restrict__ out,           // [N_EDGES]
    float* __restrict__ s_tab,         // [N_NODES]   (in d_ws)
    float* __restrict__ d_tab,         // [N_NODES]   (in d_ws)
    int*   __restrict__ barrier_ct)    // [1]         (in d_ws, pre-zeroed)
{
    const int tid      = blockIdx.x * NTHR + threadIdx.x;  // 0 .. 262143
    const int nthreads = NBLK * NTHR;                      // 262144
    const int lane     = tid & 15;

    // ---------------- Phase 1: per-node dots ----------------
    // 16 lanes per node, each lane covers 8 of 128 floats (2x float4).
    const f32x4* wv = reinterpret_cast<const f32x4*>(w);
    const f32x4 ws0 = wv[lane];
    const f32x4 ws1 = wv[lane + 16];
    const f32x4 wd0 = wv[lane + 32];
    const f32x4 wd1 = wv[lane + 48];

    const int group   = tid >> 4;        // 0 .. 16383
    const int ngroups = nthreads >> 4;   // 16384

    #pragma unroll 2
    for (int node = group; node < N_NODES; node += ngroups) {
        const f32x4* xs = reinterpret_cast<const f32x4*>(x_src + (size_t)node * HIDDEN);
        const f32x4* xd = reinterpret_cast<const f32x4*>(x_dst + (size_t)node * HIDDEN);
        const f32x4 a0 = xs[lane];
        const f32x4 a1 = xs[lane + 16];
        const f32x4 b0 = xd[lane];
        const f32x4 b1 = xd[lane + 16];

        float ss = a0.x*ws0.x + a0.y*ws0.y + a0.z*ws0.z + a0.w*ws0.w
                 + a1.x*ws1.x + a1.y*ws1.y + a1.z*ws1.z + a1.w*ws1.w;
        float dd = b0.x*wd0.x + b0.y*wd0.y + b0.z*wd0.z + b0.w*wd0.w
                 + b1.x*wd1.x + b1.y*wd1.y + b1.z*wd1.z + b1.w*wd1.w;

        #pragma unroll
        for (int off = 8; off; off >>= 1) {
            ss += __shfl_xor(ss, off);
            dd += __shfl_xor(dd, off);
        }
        if (lane == 0) {
            s_tab[node] = ss;
            d_tab[node] = dd;
        }
    }

    // ---------------- Grid-wide barrier ----------------
    __syncthreads();
    if (threadIdx.x == 0) {
        // Publish our table writes (one L2 writeback), count in.
        __hip_atomic_fetch_add(barrier_ct, 1, __ATOMIC_RELEASE, __HIP_MEMORY_SCOPE_AGENT);
        // Cheap relaxed polls — no cache maintenance per iteration.
        while (__hip_atomic_load(barrier_ct, __ATOMIC_RELAXED, __HIP_MEMORY_SCOPE_AGENT) < NBLK) {
            __builtin_amdgcn_s_sleep(8);
        }
        // One acquire: invalidate stale lines so we see all blocks' tables.
        __builtin_amdgcn_fence(__ATOMIC_ACQUIRE, "agent");
    }
    __syncthreads();

    // ---------------- Phase 2: per-edge gather ----------------
    // 8 edges per thread, one pass (250000 active threads of 262144).
    const float bv = bias[0];
    const i32x4* ia = reinterpret_cast<const i32x4*>(idx);
    const i32x4* ib = reinterpret_cast<const i32x4*>(idx + N_EDGES);
    f32x4* ov = reinterpret_cast<f32x4*>(out);
    const int nt = N_EDGES / 8;          // 250000

    if (tid < nt) {
        const int t = tid;
        const i32x4 a0 = __builtin_nontemporal_load(ia + 2 * t);
        const i32x4 a1 = __builtin_nontemporal_load(ia + 2 * t + 1);
        const i32x4 b0 = __builtin_nontemporal_load(ib + 2 * t);
        const i32x4 b1 = __builtin_nontemporal_load(ib + 2 * t + 1);

        f32x4 o0, o1;
        o0.x = s_tab[a0.x] + d_tab[b0.x] + bv;
        o0.y = s_tab[a0.y] + d_tab[b0.y] + bv;
        o0.z = s_tab[a0.z] + d_tab[b0.z] + bv;
        o0.w = s_tab[a0.w] + d_tab[b0.w] + bv;
        o1.x = s_tab[a1.x] + d_tab[b1.x] + bv;
        o1.y = s_tab[a1.y] + d_tab[b1.y] + bv;
        o1.z = s_tab[a1.z] + d_tab[b1.z] + bv;
        o1.w = s_tab[a1.w] + d_tab[b1.w] + bv;

        __builtin_nontemporal_store(o0, ov + 2 * t);
        __builtin_nontemporal_store(o1, ov + 2 * t + 1);
    }
}

extern "C" void kernel_launch(void* const* d_in, const int* in_sizes, int n_in,
                              void* d_out, int out_size, void* d_ws, size_t ws_size,
                              hipStream_t stream) {
    const float* x_src = (const float*)d_in[0];
    const float* x_dst = (const float*)d_in[1];
    const int*   idx   = (const int*)d_in[2];
    const float* w     = (const float*)d_in[3];
    const float* bias  = (const float*)d_in[4];
    float* out = (float*)d_out;

    float* s_tab = (float*)d_ws;
    float* d_tab = s_tab + N_NODES;
    int*   barrier_ct = (int*)(d_tab + N_NODES);

    // Reset the barrier counter every call (deterministic across graph replays).
    hipMemsetAsync(barrier_ct, 0, sizeof(int), stream);

    fused_edge_decoder<<<NBLK, NTHR, 0, stream>>>(
        x_src, x_dst, idx, w, bias, out, s_tab, d_tab, barrier_ct);
}

// Round 8
// 80.363 us; speedup vs baseline: 2.0326x; 1.7978x over previous
//
#include <hip/hip_runtime.h>

#define HIDDEN  128
#define N_NODES 100000
#define N_EDGES 2000000
#define NBLK    1024
#define NTHR    256
#define NCTR    64          // spread arrival counters over 64 cache lines
#define CTR_STRIDE 32       // 32 ints = 128 B between counters

typedef float f32x4 __attribute__((ext_vector_type(4)));
typedef int   i32x4 __attribute__((ext_vector_type(4)));

// Fused edge decoder with a master-block grid barrier.
//
// Round-7 lesson: a single counter that is simultaneously fetch_add'ed by
// arrivals and polled by ~1000 spinners serializes at ~150ns/arrival
// (ownership ping-pong) -> ~150us. Here arrivals go to 64 spread lines
// (parallel, reader-free), only block 0 sweeps them, and everyone else
// polls a read-only 'go' flag (no RMW contention).
__global__ __launch_bounds__(NTHR) void fused_edge_decoder(
    const float* __restrict__ x_src,
    const float* __restrict__ x_dst,
    const int*   __restrict__ idx,     // [2*N_EDGES]
    const float* __restrict__ w,       // [256]
    const float* __restrict__ bias,    // [1]
    float* __restrict__ out,           // [N_EDGES]
    float* __restrict__ s_tab,         // [N_NODES] (d_ws)
    float* __restrict__ d_tab,         // [N_NODES] (d_ws)
    int*   __restrict__ cnt,           // [NCTR*CTR_STRIDE] (d_ws, zeroed)
    int*   __restrict__ go)            // [1] (d_ws, zeroed)
{
    const int tid      = blockIdx.x * NTHR + threadIdx.x;  // 0 .. 262143
    const int nthreads = NBLK * NTHR;                      // 262144
    const int lane     = tid & 15;

    // ---------------- Phase 1: per-node dots ----------------
    // 16 lanes per node, each lane covers 8 of 128 floats (2x float4).
    const f32x4* wv = reinterpret_cast<const f32x4*>(w);
    const f32x4 ws0 = wv[lane];
    const f32x4 ws1 = wv[lane + 16];
    const f32x4 wd0 = wv[lane + 32];
    const f32x4 wd1 = wv[lane + 48];

    const int group   = tid >> 4;        // 0 .. 16383
    const int ngroups = nthreads >> 4;   // 16384

    #pragma unroll 2
    for (int node = group; node < N_NODES; node += ngroups) {
        const f32x4* xs = reinterpret_cast<const f32x4*>(x_src + (size_t)node * HIDDEN);
        const f32x4* xd = reinterpret_cast<const f32x4*>(x_dst + (size_t)node * HIDDEN);
        const f32x4 a0 = xs[lane];
        const f32x4 a1 = xs[lane + 16];
        const f32x4 b0 = xd[lane];
        const f32x4 b1 = xd[lane + 16];

        float ss = a0.x*ws0.x + a0.y*ws0.y + a0.z*ws0.z + a0.w*ws0.w
                 + a1.x*ws1.x + a1.y*ws1.y + a1.z*ws1.z + a1.w*ws1.w;
        float dd = b0.x*wd0.x + b0.y*wd0.y + b0.z*wd0.z + b0.w*wd0.w
                 + b1.x*wd1.x + b1.y*wd1.y + b1.z*wd1.z + b1.w*wd1.w;

        #pragma unroll
        for (int off = 8; off; off >>= 1) {
            ss += __shfl_xor(ss, off);
            dd += __shfl_xor(dd, off);
        }
        if (lane == 0) {
            s_tab[node] = ss;
            d_tab[node] = dd;
        }
    }

    // ---------------- Grid-wide barrier (master-block) ----------------
    __syncthreads();
    if (threadIdx.x < 64) {  // leader wave only
        if (threadIdx.x == 0) {
            // Publish table writes; arrivals spread over 64 independent lines.
            __hip_atomic_fetch_add(&cnt[(blockIdx.x & (NCTR - 1)) * CTR_STRIDE],
                                   1, __ATOMIC_RELEASE, __HIP_MEMORY_SCOPE_AGENT);
        }
        if (blockIdx.x == 0) {
            // Master: lane i sweeps cnt[i]; one wave load per poll.
            int sum = 0;
            do {
                __builtin_amdgcn_s_sleep(2);
                int v = __hip_atomic_load(&cnt[threadIdx.x * CTR_STRIDE],
                                          __ATOMIC_RELAXED, __HIP_MEMORY_SCOPE_AGENT);
                sum = v;
                #pragma unroll
                for (int off = 32; off; off >>= 1) sum += __shfl_xor(sum, off);
            } while (sum < NBLK);
            if (threadIdx.x == 0) {
                // Pair with workers' release-adds, then publish 'go'.
                __builtin_amdgcn_fence(__ATOMIC_ACQUIRE, "agent");
                __hip_atomic_store(go, 1, __ATOMIC_RELEASE, __HIP_MEMORY_SCOPE_AGENT);
            }
        } else if (threadIdx.x == 0) {
            // Workers: poll the read-only flag (no RMW -> no line ping-pong).
            while (__hip_atomic_load(go, __ATOMIC_RELAXED, __HIP_MEMORY_SCOPE_AGENT) == 0) {
                __builtin_amdgcn_s_sleep(32);
            }
            __builtin_amdgcn_fence(__ATOMIC_ACQUIRE, "agent");
        }
    }
    __syncthreads();

    // ---------------- Phase 2: per-edge gather ----------------
    // 8 edges per thread, one pass (250000 active threads of 262144).
    const float bv = bias[0];
    const i32x4* ia = reinterpret_cast<const i32x4*>(idx);
    const i32x4* ib = reinterpret_cast<const i32x4*>(idx + N_EDGES);
    f32x4* ov = reinterpret_cast<f32x4*>(out);
    const int nt = N_EDGES / 8;          // 250000

    if (tid < nt) {
        const int t = tid;
        const i32x4 a0 = __builtin_nontemporal_load(ia + 2 * t);
        const i32x4 a1 = __builtin_nontemporal_load(ia + 2 * t + 1);
        const i32x4 b0 = __builtin_nontemporal_load(ib + 2 * t);
        const i32x4 b1 = __builtin_nontemporal_load(ib + 2 * t + 1);

        f32x4 o0, o1;
        o0.x = s_tab[a0.x] + d_tab[b0.x] + bv;
        o0.y = s_tab[a0.y] + d_tab[b0.y] + bv;
        o0.z = s_tab[a0.z] + d_tab[b0.z] + bv;
        o0.w = s_tab[a0.w] + d_tab[b0.w] + bv;
        o1.x = s_tab[a1.x] + d_tab[b1.x] + bv;
        o1.y = s_tab[a1.y] + d_tab[b1.y] + bv;
        o1.z = s_tab[a1.z] + d_tab[b1.z] + bv;
        o1.w = s_tab[a1.w] + d_tab[b1.w] + bv;

        __builtin_nontemporal_store(o0, ov + 2 * t);
        __builtin_nontemporal_store(o1, ov + 2 * t + 1);
    }
}

extern "C" void kernel_launch(void* const* d_in, const int* in_sizes, int n_in,
                              void* d_out, int out_size, void* d_ws, size_t ws_size,
                              hipStream_t stream) {
    const float* x_src = (const float*)d_in[0];
    const float* x_dst = (const float*)d_in[1];
    const int*   idx   = (const int*)d_in[2];
    const float* w     = (const float*)d_in[3];
    const float* bias  = (const float*)d_in[4];
    float* out = (float*)d_out;

    float* s_tab = (float*)d_ws;
    float* d_tab = s_tab + N_NODES;
    int*   cnt   = (int*)(d_tab + N_NODES);          // 64 counters, 128B apart
    int*   go    = cnt + NCTR * CTR_STRIDE;          // own cache line after them

    // Reset barrier state every call (deterministic across graph replays).
    hipMemsetAsync(cnt, 0, (NCTR * CTR_STRIDE + 1) * sizeof(int), stream);

    fused_edge_decoder<<<NBLK, NTHR, 0, stream>>>(
        x_src, x_dst, idx, w, bias, out, s_tab, d_tab, cnt, go);
}

// Round 9
// 47.125 us; speedup vs baseline: 3.4662x; 1.7053x over previous
//
#include <hip/hip_runtime.h>

#define HIDDEN  128
#define N_NODES 100000
#define N_EDGES 2000000
#define NBLK    1024
#define NTHR    256
#define NCTR    64          // arrival counters spread over 64 cache lines
#define NGO     8           // go flags spread over 8 cache lines
#define CTR_STRIDE 32       // 32 ints = 128 B between slots

typedef float f32x4 __attribute__((ext_vector_type(4)));
typedef int   i32x4 __attribute__((ext_vector_type(4)));

// Fused edge decoder, grid barrier with NO release/acquire cache-ops in the
// hot path (round-8 lesson: each agent-scope RELEASE = L2 writeback walk,
// ~75us aggregate at 1024 blocks). Tables are published by WRITE-THROUGH
// (agent-scope relaxed atomic stores -> visible at LLC), arrivals are
// relaxed adds on spread lines, workers poll read-only spread 'go' flags.
__global__ __launch_bounds__(NTHR) void fused_edge_decoder(
    const float* __restrict__ x_src,
    const float* __restrict__ x_dst,
    const int*   __restrict__ idx,     // [2*N_EDGES]
    const float* __restrict__ w,       // [256]
    const float* __restrict__ bias,    // [1]
    float* __restrict__ out,           // [N_EDGES]
    float* __restrict__ s_tab,         // [N_NODES] (d_ws)
    float* __restrict__ d_tab,         // [N_NODES] (d_ws)
    int*   __restrict__ cnt,           // [NCTR*CTR_STRIDE] (d_ws, zeroed)
    int*   __restrict__ go)            // [NGO*CTR_STRIDE]  (d_ws, zeroed)
{
    const int tid      = blockIdx.x * NTHR + threadIdx.x;  // 0 .. 262143
    const int nthreads = NBLK * NTHR;                      // 262144
    const int lane     = tid & 15;

    // ---------------- Phase 1: per-node dots ----------------
    // 16 lanes per node, each lane covers 8 of 128 floats (2x float4).
    const f32x4* wv = reinterpret_cast<const f32x4*>(w);
    const f32x4 ws0 = wv[lane];
    const f32x4 ws1 = wv[lane + 16];
    const f32x4 wd0 = wv[lane + 32];
    const f32x4 wd1 = wv[lane + 48];

    const int group   = tid >> 4;        // 0 .. 16383
    const int ngroups = nthreads >> 4;   // 16384

    #pragma unroll 2
    for (int node = group; node < N_NODES; node += ngroups) {
        const f32x4* xs = reinterpret_cast<const f32x4*>(x_src + (size_t)node * HIDDEN);
        const f32x4* xd = reinterpret_cast<const f32x4*>(x_dst + (size_t)node * HIDDEN);
        const f32x4 a0 = xs[lane];
        const f32x4 a1 = xs[lane + 16];
        const f32x4 b0 = xd[lane];
        const f32x4 b1 = xd[lane + 16];

        float ss = a0.x*ws0.x + a0.y*ws0.y + a0.z*ws0.z + a0.w*ws0.w
                 + a1.x*ws1.x + a1.y*ws1.y + a1.z*ws1.z + a1.w*ws1.w;
        float dd = b0.x*wd0.x + b0.y*wd0.y + b0.z*wd0.z + b0.w*wd0.w
                 + b1.x*wd1.x + b1.y*wd1.y + b1.z*wd1.z + b1.w*wd1.w;

        #pragma unroll
        for (int off = 8; off; off >>= 1) {
            ss += __shfl_xor(ss, off);
            dd += __shfl_xor(dd, off);
        }
        if (lane == 0) {
            // Write-through to the coherence point: no L2 flush needed later.
            __hip_atomic_store(&s_tab[node], ss, __ATOMIC_RELAXED, __HIP_MEMORY_SCOPE_AGENT);
            __hip_atomic_store(&d_tab[node], dd, __ATOMIC_RELAXED, __HIP_MEMORY_SCOPE_AGENT);
        }
    }

    // ---------------- Grid-wide barrier (no cache-maintenance ops) --------
    __syncthreads();
    if (threadIdx.x == 0) {
        // Ensure our write-through stores have retired, then count in
        // (relaxed RMW on one of 64 spread lines; no flush, no pollers here).
        asm volatile("s_waitcnt vmcnt(0)" ::: "memory");
        __hip_atomic_fetch_add(&cnt[(blockIdx.x & (NCTR - 1)) * CTR_STRIDE],
                               1, __ATOMIC_RELAXED, __HIP_MEMORY_SCOPE_AGENT);
    }
    if (blockIdx.x == 0) {
        if (threadIdx.x < 64) {
            // Master: lane i sweeps cnt[i]; one wave load per poll round.
            int sum = 0;
            do {
                __builtin_amdgcn_s_sleep(2);
                sum = __hip_atomic_load(&cnt[threadIdx.x * CTR_STRIDE],
                                        __ATOMIC_RELAXED, __HIP_MEMORY_SCOPE_AGENT);
                #pragma unroll
                for (int off = 32; off; off >>= 1) sum += __shfl_xor(sum, off);
            } while (sum < NBLK);
            if (threadIdx.x < NGO) {
                __hip_atomic_store(&go[threadIdx.x * CTR_STRIDE], 1,
                                   __ATOMIC_RELAXED, __HIP_MEMORY_SCOPE_AGENT);
            }
        }
    } else if (threadIdx.x == 0) {
        // Workers: poll a read-only spread flag; no RMW, no fence.
        int* myg = &go[(blockIdx.x & (NGO - 1)) * CTR_STRIDE];
        while (__hip_atomic_load(myg, __ATOMIC_RELAXED, __HIP_MEMORY_SCOPE_AGENT) == 0) {
            __builtin_amdgcn_s_sleep(16);
        }
    }
    __syncthreads();

    // ---------------- Phase 2: per-edge gather ----------------
    // 8 edges per thread, one pass (250000 active threads of 262144).
    // Table loads are plain (cacheable): local caches hold no stale copies
    // of d_ws this dispatch, so misses fetch the fresh LLC values.
    const float bv = bias[0];
    const i32x4* ia = reinterpret_cast<const i32x4*>(idx);
    const i32x4* ib = reinterpret_cast<const i32x4*>(idx + N_EDGES);
    f32x4* ov = reinterpret_cast<f32x4*>(out);
    const int nt = N_EDGES / 8;          // 250000

    if (tid < nt) {
        const int t = tid;
        const i32x4 a0 = __builtin_nontemporal_load(ia + 2 * t);
        const i32x4 a1 = __builtin_nontemporal_load(ia + 2 * t + 1);
        const i32x4 b0 = __builtin_nontemporal_load(ib + 2 * t);
        const i32x4 b1 = __builtin_nontemporal_load(ib + 2 * t + 1);

        f32x4 o0, o1;
        o0.x = s_tab[a0.x] + d_tab[b0.x] + bv;
        o0.y = s_tab[a0.y] + d_tab[b0.y] + bv;
        o0.z = s_tab[a0.z] + d_tab[b0.z] + bv;
        o0.w = s_tab[a0.w] + d_tab[b0.w] + bv;
        o1.x = s_tab[a1.x] + d_tab[b1.x] + bv;
        o1.y = s_tab[a1.y] + d_tab[b1.y] + bv;
        o1.z = s_tab[a1.z] + d_tab[b1.z] + bv;
        o1.w = s_tab[a1.w] + d_tab[b1.w] + bv;

        __builtin_nontemporal_store(o0, ov + 2 * t);
        __builtin_nontemporal_store(o1, ov + 2 * t + 1);
    }
}

extern "C" void kernel_launch(void* const* d_in, const int* in_sizes, int n_in,
                              void* d_out, int out_size, void* d_ws, size_t ws_size,
                              hipStream_t stream) {
    const float* x_src = (const float*)d_in[0];
    const float* x_dst = (const float*)d_in[1];
    const int*   idx   = (const int*)d_in[2];
    const float* w     = (const float*)d_in[3];
    const float* bias  = (const float*)d_in[4];
    float* out = (float*)d_out;

    float* s_tab = (float*)d_ws;
    float* d_tab = s_tab + N_NODES;
    int*   cnt   = (int*)(d_tab + N_NODES);          // 64 counters, 128B apart
    int*   go    = cnt + NCTR * CTR_STRIDE;          // 8 flags, 128B apart

    // Reset barrier state every call (deterministic across graph replays).
    hipMemsetAsync(cnt, 0, (NCTR + NGO) * CTR_STRIDE * sizeof(int), stream);

    fused_edge_decoder<<<NBLK, NTHR, 0, stream>>>(
        x_src, x_dst, idx, w, bias, out, s_tab, d_tab, cnt, go);
}

// Round 10
// 45.878 us; speedup vs baseline: 3.5604x; 1.0272x over previous
//
#include <hip/hip_runtime.h>

#define HIDDEN  128
#define N_NODES 100000
#define N_EDGES 2000000
#define NBLK    2048        // 8 blocks/CU x 256 thr = 32 waves/CU (residency max)
#define NTHR    256
#define NCTR    64          // arrival counters spread over 64 cache lines
#define NGO     8           // go flags spread over 8 cache lines
#define CTR_STRIDE 32       // 32 ints = 128 B between slots

typedef float f32x4 __attribute__((ext_vector_type(4)));
typedef int   i32x4 __attribute__((ext_vector_type(4)));

// Fused edge decoder. Barrier lessons so far: arrivals = relaxed adds on 64
// spread lines (no pollers on them); tables published by WRITE-THROUGH
// (agent-scope relaxed stores -> LLC), so no release/acquire cache-ops
// anywhere; master block sweeps and raises 8 spread read-only go flags.
// This round: full occupancy (2048 blocks) + pre-barrier idx prefetch.
__global__ __launch_bounds__(NTHR) void fused_edge_decoder(
    const float* __restrict__ x_src,
    const float* __restrict__ x_dst,
    const int*   __restrict__ idx,     // [2*N_EDGES]
    const float* __restrict__ w,       // [256]
    const float* __restrict__ bias,    // [1]
    float* __restrict__ out,           // [N_EDGES]
    float* __restrict__ s_tab,         // [N_NODES] (d_ws)
    float* __restrict__ d_tab,         // [N_NODES] (d_ws)
    int*   __restrict__ cnt,           // [NCTR*CTR_STRIDE] (d_ws, zeroed)
    int*   __restrict__ go)            // [NGO*CTR_STRIDE]  (d_ws, zeroed)
{
    const int tid      = blockIdx.x * NTHR + threadIdx.x;  // 0 .. 524287
    const int nthreads = NBLK * NTHR;                      // 524288
    const int lane     = tid & 15;

    // ---- Prefetch phase-2 indices (independent of the barrier): 4 edges
    // per thread. Loads issue now and retire under phase 1.
    const int nt = N_EDGES / 4;          // 500000 active phase-2 threads
    i32x4 pa = {0, 0, 0, 0}, pb = {0, 0, 0, 0};
    if (tid < nt) {
        pa = __builtin_nontemporal_load(reinterpret_cast<const i32x4*>(idx) + tid);
        pb = __builtin_nontemporal_load(reinterpret_cast<const i32x4*>(idx + N_EDGES) + tid);
    }

    // ---------------- Phase 1: per-node dots ----------------
    // 16 lanes per node, each lane covers 8 of 128 floats (2x float4).
    const f32x4* wv = reinterpret_cast<const f32x4*>(w);
    const f32x4 ws0 = wv[lane];
    const f32x4 ws1 = wv[lane + 16];
    const f32x4 wd0 = wv[lane + 32];
    const f32x4 wd1 = wv[lane + 48];

    const int group   = tid >> 4;        // 0 .. 32767
    const int ngroups = nthreads >> 4;   // 32768

    for (int node = group; node < N_NODES; node += ngroups) {
        const f32x4* xs = reinterpret_cast<const f32x4*>(x_src + (size_t)node * HIDDEN);
        const f32x4* xd = reinterpret_cast<const f32x4*>(x_dst + (size_t)node * HIDDEN);
        const f32x4 a0 = xs[lane];
        const f32x4 a1 = xs[lane + 16];
        const f32x4 b0 = xd[lane];
        const f32x4 b1 = xd[lane + 16];

        float ss = a0.x*ws0.x + a0.y*ws0.y + a0.z*ws0.z + a0.w*ws0.w
                 + a1.x*ws1.x + a1.y*ws1.y + a1.z*ws1.z + a1.w*ws1.w;
        float dd = b0.x*wd0.x + b0.y*wd0.y + b0.z*wd0.z + b0.w*wd0.w
                 + b1.x*wd1.x + b1.y*wd1.y + b1.z*wd1.z + b1.w*wd1.w;

        #pragma unroll
        for (int off = 8; off; off >>= 1) {
            ss += __shfl_xor(ss, off);
            dd += __shfl_xor(dd, off);
        }
        if (lane == 0) {
            // Write-through to the coherence point: no L2 flush needed later.
            __hip_atomic_store(&s_tab[node], ss, __ATOMIC_RELAXED, __HIP_MEMORY_SCOPE_AGENT);
            __hip_atomic_store(&d_tab[node], dd, __ATOMIC_RELAXED, __HIP_MEMORY_SCOPE_AGENT);
        }
    }

    // ---------------- Grid-wide barrier (no cache-maintenance ops) --------
    __syncthreads();
    if (threadIdx.x == 0) {
        // Ensure our write-through stores retired, then count in (relaxed
        // RMW on one of 64 spread lines; no flush, no pollers there).
        asm volatile("s_waitcnt vmcnt(0)" ::: "memory");
        __hip_atomic_fetch_add(&cnt[(blockIdx.x & (NCTR - 1)) * CTR_STRIDE],
                               1, __ATOMIC_RELAXED, __HIP_MEMORY_SCOPE_AGENT);
    }
    if (blockIdx.x == 0) {
        if (threadIdx.x < 64) {
            // Master: lane i sweeps cnt[i]; one wave load per poll round.
            int sum = 0;
            do {
                __builtin_amdgcn_s_sleep(2);
                sum = __hip_atomic_load(&cnt[threadIdx.x * CTR_STRIDE],
                                        __ATOMIC_RELAXED, __HIP_MEMORY_SCOPE_AGENT);
                #pragma unroll
                for (int off = 32; off; off >>= 1) sum += __shfl_xor(sum, off);
            } while (sum < NBLK);
            if (threadIdx.x < NGO) {
                __hip_atomic_store(&go[threadIdx.x * CTR_STRIDE], 1,
                                   __ATOMIC_RELAXED, __HIP_MEMORY_SCOPE_AGENT);
            }
        }
    } else if (threadIdx.x == 0) {
        // Workers: poll a read-only spread flag; no RMW, no fence.
        int* myg = &go[(blockIdx.x & (NGO - 1)) * CTR_STRIDE];
        while (__hip_atomic_load(myg, __ATOMIC_RELAXED, __HIP_MEMORY_SCOPE_AGENT) == 0) {
            __builtin_amdgcn_s_sleep(8);
        }
    }
    __syncthreads();

    // ---------------- Phase 2: per-edge gather ----------------
    // Indices already in registers; post-barrier path = gathers + store.
    // Table loads are plain (cacheable): local caches hold no stale d_ws
    // lines this dispatch, so misses fetch fresh LLC values.
    if (tid < nt) {
        const float bv = bias[0];
        f32x4 o;
        o.x = s_tab[pa.x] + d_tab[pb.x] + bv;
        o.y = s_tab[pa.y] + d_tab[pb.y] + bv;
        o.z = s_tab[pa.z] + d_tab[pb.z] + bv;
        o.w = s_tab[pa.w] + d_tab[pb.w] + bv;
        __builtin_nontemporal_store(o, reinterpret_cast<f32x4*>(out) + tid);
    }
}

extern "C" void kernel_launch(void* const* d_in, const int* in_sizes, int n_in,
                              void* d_out, int out_size, void* d_ws, size_t ws_size,
                              hipStream_t stream) {
    const float* x_src = (const float*)d_in[0];
    const float* x_dst = (const float*)d_in[1];
    const int*   idx   = (const int*)d_in[2];
    const float* w     = (const float*)d_in[3];
    const float* bias  = (const float*)d_in[4];
    float* out = (float*)d_out;

    float* s_tab = (float*)d_ws;
    float* d_tab = s_tab + N_NODES;
    int*   cnt   = (int*)(d_tab + N_NODES);          // 64 counters, 128B apart
    int*   go    = cnt + NCTR * CTR_STRIDE;          // 8 flags, 128B apart

    // Reset barrier state every call (deterministic across graph replays).
    hipMemsetAsync(cnt, 0, (NCTR + NGO) * CTR_STRIDE * sizeof(int), stream);

    fused_edge_decoder<<<NBLK, NTHR, 0, stream>>>(
        x_src, x_dst, idx, w, bias, out, s_tab, d_tab, cnt, go);
}

// Round 11
// 43.849 us; speedup vs baseline: 3.7251x; 1.0463x over previous
//
#include <hip/hip_runtime.h>

// DIAGNOSTIC ROUND: both kernels repeat their full work 8x (idempotent:
// every pass recomputes and rewrites the same values). This inflates their
// durations above the harness's 39us poison-fills so they appear in the
// top-5 profile rows, giving per-kernel time (/8), per-kernel FETCH, and
// inter-dispatch gaps via timestamps. Correctness is unchanged.

#define HIDDEN  128
#define N_NODES 100000
#define N_EDGES 2000000
#define REPEAT  8

typedef float f32x4 __attribute__((ext_vector_type(4)));
typedef int   i32x4 __attribute__((ext_vector_type(4)));

// Kernel 1: per-node dot products (16 lanes/node, 2x float4 per lane).
__global__ __launch_bounds__(256) void node_dots_x8(
    const float* __restrict__ x_src,
    const float* __restrict__ x_dst,
    const float* __restrict__ w,    // [256]
    float* __restrict__ s_tab,      // [N_NODES]
    float* __restrict__ d_tab)      // [N_NODES]
{
    int gid  = blockIdx.x * 256 + threadIdx.x;
    int node = gid >> 4;
    int lane = gid & 15;
    if (node >= N_NODES) return;

    const f32x4* wv = reinterpret_cast<const f32x4*>(w);
    const f32x4 ws0 = wv[lane];
    const f32x4 ws1 = wv[lane + 16];
    const f32x4 wd0 = wv[lane + 32];
    const f32x4 wd1 = wv[lane + 48];

    const f32x4* xs = reinterpret_cast<const f32x4*>(x_src + (size_t)node * HIDDEN);
    const f32x4* xd = reinterpret_cast<const f32x4*>(x_dst + (size_t)node * HIDDEN);

    for (int r = 0; r < REPEAT; ++r) {
        const f32x4 a0 = xs[lane];
        const f32x4 a1 = xs[lane + 16];
        const f32x4 b0 = xd[lane];
        const f32x4 b1 = xd[lane + 16];

        float ss = a0.x*ws0.x + a0.y*ws0.y + a0.z*ws0.z + a0.w*ws0.w
                 + a1.x*ws1.x + a1.y*ws1.y + a1.z*ws1.z + a1.w*ws1.w;
        float dd = b0.x*wd0.x + b0.y*wd0.y + b0.z*wd0.z + b0.w*wd0.w
                 + b1.x*wd1.x + b1.y*wd1.y + b1.z*wd1.z + b1.w*wd1.w;

        #pragma unroll
        for (int off = 8; off; off >>= 1) {
            ss += __shfl_xor(ss, off);
            dd += __shfl_xor(dd, off);
        }
        if (lane == 0) {
            s_tab[node] = ss;
            d_tab[node] = dd;
        }
        // Prevent the compiler from collapsing identical passes.
        asm volatile("" ::: "memory");
    }
}

// Kernel 2: per-edge gather + add, 4 edges/thread.
__global__ __launch_bounds__(256) void edge_gather_x8(
    const int* __restrict__ idx,          // [2*N_EDGES]
    const float* __restrict__ s_tab,
    const float* __restrict__ d_tab,
    const float* __restrict__ bias,       // [1]
    float* __restrict__ out)              // [N_EDGES]
{
    int t = blockIdx.x * 256 + threadIdx.x;
    if (t >= N_EDGES / 4) return;

    const float bv = bias[0];
    const i32x4* ia = reinterpret_cast<const i32x4*>(idx);
    const i32x4* ib = reinterpret_cast<const i32x4*>(idx + N_EDGES);
    f32x4* ov = reinterpret_cast<f32x4*>(out);

    for (int r = 0; r < REPEAT; ++r) {
        const i32x4 a = ia[t];
        const i32x4 b = ib[t];

        f32x4 o;
        o.x = s_tab[a.x] + d_tab[b.x] + bv;
        o.y = s_tab[a.y] + d_tab[b.y] + bv;
        o.z = s_tab[a.z] + d_tab[b.z] + bv;
        o.w = s_tab[a.w] + d_tab[b.w] + bv;

        ov[t] = o;
        asm volatile("" ::: "memory");
    }
}

extern "C" void kernel_launch(void* const* d_in, const int* in_sizes, int n_in,
                              void* d_out, int out_size, void* d_ws, size_t ws_size,
                              hipStream_t stream) {
    const float* x_src = (const float*)d_in[0];
    const float* x_dst = (const float*)d_in[1];
    const int*   idx   = (const int*)d_in[2];
    const float* w     = (const float*)d_in[3];
    const float* bias  = (const float*)d_in[4];
    float* out = (float*)d_out;

    float* s_tab = (float*)d_ws;
    float* d_tab = s_tab + N_NODES;

    {
        int total_threads = N_NODES * 16;              // 1.6M
        int blocks = (total_threads + 255) / 256;      // 6250
        node_dots_x8<<<blocks, 256, 0, stream>>>(x_src, x_dst, w, s_tab, d_tab);
    }
    {
        int threads = N_EDGES / 4;                     // 500000
        int blocks = (threads + 255) / 256;            // 1954
        edge_gather_x8<<<blocks, 256, 0, stream>>>(idx, s_tab, d_tab, bias, out);
    }
}

// Round 12
// 39.821 us; speedup vs baseline: 4.1019x; 1.1011x over previous
//
#include <hip/hip_runtime.h>

// Final structure (model from 11 rounds: dur_us = ~36us fixed harness/replay
// overhead + true kernel time; warm-replay kernel time ~3.5us with inputs
// L3-resident). Two plain kernels, no grid barrier (a fused variant pays
// ~6-10us of barrier cost against a ~3.5us workload — always loses).
// Cacheable loads for everything re-read across replays (features, idx,
// tables) so the 256MB L3 keeps serving them; NT only on the final store.

#define HIDDEN  128
#define N_NODES 100000
#define N_EDGES 2000000

typedef float f32x4 __attribute__((ext_vector_type(4)));
typedef int   i32x4 __attribute__((ext_vector_type(4)));

// Kernel 1: per-node dot products. 16 lanes per node, each lane covers
// 8 of 128 floats (2x float4) -> 512B contiguous per row, coalesced,
// 4x 16B loads in flight per thread.
__global__ __launch_bounds__(256) void node_dots_kernel(
    const float* __restrict__ x_src,
    const float* __restrict__ x_dst,
    const float* __restrict__ w,    // [256]: first 128 = w_src, next 128 = w_dst
    float* __restrict__ s_tab,      // [N_NODES]
    float* __restrict__ d_tab)      // [N_NODES]
{
    int gid  = blockIdx.x * 256 + threadIdx.x;
    int node = gid >> 4;
    int lane = gid & 15;
    if (node >= N_NODES) return;

    const f32x4* wv = reinterpret_cast<const f32x4*>(w);
    const f32x4 ws0 = wv[lane];
    const f32x4 ws1 = wv[lane + 16];
    const f32x4 wd0 = wv[lane + 32];
    const f32x4 wd1 = wv[lane + 48];

    const f32x4* xs = reinterpret_cast<const f32x4*>(x_src + (size_t)node * HIDDEN);
    const f32x4* xd = reinterpret_cast<const f32x4*>(x_dst + (size_t)node * HIDDEN);
    const f32x4 a0 = xs[lane];
    const f32x4 a1 = xs[lane + 16];
    const f32x4 b0 = xd[lane];
    const f32x4 b1 = xd[lane + 16];

    float ss = a0.x*ws0.x + a0.y*ws0.y + a0.z*ws0.z + a0.w*ws0.w
             + a1.x*ws1.x + a1.y*ws1.y + a1.z*ws1.z + a1.w*ws1.w;
    float dd = b0.x*wd0.x + b0.y*wd0.y + b0.z*wd0.z + b0.w*wd0.w
             + b1.x*wd1.x + b1.y*wd1.y + b1.z*wd1.z + b1.w*wd1.w;

    #pragma unroll
    for (int off = 8; off; off >>= 1) {
        ss += __shfl_xor(ss, off);
        dd += __shfl_xor(dd, off);
    }
    if (lane == 0) {
        s_tab[node] = ss;
        d_tab[node] = dd;
    }
}

// Kernel 2: per-edge gather + add, 8 edges per thread. Tables (800KB) are
// L2/L3-resident; idx loads stay cacheable so they remain L3-warm across
// replays; only the output store is nontemporal (write-once stream).
__global__ __launch_bounds__(256) void edge_kernel(
    const int* __restrict__ idx,          // [2*N_EDGES], row0 = src, row1 = dst
    const float* __restrict__ s_tab,
    const float* __restrict__ d_tab,
    const float* __restrict__ bias,       // [1]
    float* __restrict__ out)              // [N_EDGES]
{
    int t = blockIdx.x * 256 + threadIdx.x;
    if (t >= N_EDGES / 8) return;

    const i32x4* ia = reinterpret_cast<const i32x4*>(idx);
    const i32x4* ib = reinterpret_cast<const i32x4*>(idx + N_EDGES);
    const i32x4 a0 = ia[2 * t];
    const i32x4 a1 = ia[2 * t + 1];
    const i32x4 b0 = ib[2 * t];
    const i32x4 b1 = ib[2 * t + 1];
    const float bv = bias[0];

    f32x4 o0, o1;
    o0.x = s_tab[a0.x] + d_tab[b0.x] + bv;
    o0.y = s_tab[a0.y] + d_tab[b0.y] + bv;
    o0.z = s_tab[a0.z] + d_tab[b0.z] + bv;
    o0.w = s_tab[a0.w] + d_tab[b0.w] + bv;
    o1.x = s_tab[a1.x] + d_tab[b1.x] + bv;
    o1.y = s_tab[a1.y] + d_tab[b1.y] + bv;
    o1.z = s_tab[a1.z] + d_tab[b1.z] + bv;
    o1.w = s_tab[a1.w] + d_tab[b1.w] + bv;

    f32x4* ov = reinterpret_cast<f32x4*>(out);
    __builtin_nontemporal_store(o0, ov + 2 * t);
    __builtin_nontemporal_store(o1, ov + 2 * t + 1);
}

extern "C" void kernel_launch(void* const* d_in, const int* in_sizes, int n_in,
                              void* d_out, int out_size, void* d_ws, size_t ws_size,
                              hipStream_t stream) {
    const float* x_src = (const float*)d_in[0];
    const float* x_dst = (const float*)d_in[1];
    const int*   idx   = (const int*)d_in[2];
    const float* w     = (const float*)d_in[3];
    const float* bias  = (const float*)d_in[4];
    float* out = (float*)d_out;

    float* s_tab = (float*)d_ws;
    float* d_tab = s_tab + N_NODES;

    // Kernel 1: 16 threads per node.
    {
        int total_threads = N_NODES * 16;              // 1.6M
        int blocks = (total_threads + 255) / 256;      // 6250
        node_dots_kernel<<<blocks, 256, 0, stream>>>(x_src, x_dst, w, s_tab, d_tab);
    }
    // Kernel 2: 8 edges per thread.
    {
        int threads = N_EDGES / 8;                     // 250000
        int blocks = (threads + 255) / 256;            // 977
        edge_kernel<<<blocks, 256, 0, stream>>>(idx, s_tab, d_tab, bias, out);
    }
}